// Round 2
// baseline (496.735 us; speedup 1.0000x reference)
//
#include <hip/hip_runtime.h>
#include <cstdint>

typedef unsigned short u16;
typedef unsigned long long u64;

__device__ __forceinline__ float b2f(u16 u){
  union { uint32_t i; float f; } v; v.i = ((uint32_t)u) << 16; return v.f;
}
__device__ __forceinline__ u16 f2b(float f){
  union { float f; uint32_t i; } v; v.f = f;
  uint32_t r = v.i + 0x7FFFu + ((v.i >> 16) & 1u);   // RNE
  return (u16)(r >> 16);
}
__device__ __forceinline__ float sigmoidf(float x){ return 1.0f / (1.0f + __expf(-x)); }

// ---------------------------------------------------------------- K1: ghat[b,h]
__global__ void k_pre(const float* __restrict__ nh, const float* __restrict__ Wg,
                      const float* __restrict__ bg, float* __restrict__ ghat){
  int b = threadIdx.x >> 6, h = threadIdx.x & 63;
  float g = bg[h];
  for (int d = 0; d < 64; ++d) g += nh[b*64 + d] * Wg[d*64 + h];
  float ss = g * g;
  #pragma unroll
  for (int o = 32; o > 0; o >>= 1) ss += __shfl_xor(ss, o, 64);
  ghat[b*64 + h] = g / (sqrtf(ss) + 1e-30f);
}

// ------------------------------------------- K2: Xk = all_w@Wwk+bwk, Xs = all_w@Wws+bws
__global__ __launch_bounds__(256) void k_xform(
    const float* __restrict__ w0, const float* __restrict__ w1,
    const float* __restrict__ Wwk, const float* __restrict__ bwk,
    const float* __restrict__ Wws, const float* __restrict__ bws,
    float* __restrict__ Xk, float* __restrict__ Xs){
  __shared__ float sWk[4096], sWs[4096];
  int tid = threadIdx.x;
  for (int i = tid; i < 1024; i += 256){
    ((float4*)sWk)[i] = ((const float4*)Wwk)[i];
    ((float4*)sWs)[i] = ((const float4*)Wws)[i];
  }
  __syncthreads();
  int lane = tid & 63, wave = tid >> 6;
  float bk = bwk[lane], bs = bws[lane];
  for (int t = 0; t < 4; ++t){
    int row = blockIdx.x*4 + wave + t*2048;       // row = b*4096 + n
    int b = row >> 12, n = row & 4095;
    float aw = (n < 2048) ? w0[((size_t)(b*2048 + n))*64 + lane]
                          : w1[((size_t)(b*2048 + n - 2048))*64 + lane];
    float xk = bk, xs = bs;
    #pragma unroll 8
    for (int d = 0; d < 64; ++d){
      float a = __shfl(aw, d, 64);
      xk += a * sWk[d*64 + lane];
      xs += a * sWs[d*64 + lane];
    }
    Xk[(size_t)row*64 + lane] = xk;
    Xs[(size_t)row*64 + lane] = xs;
  }
}

// ------------- K3: out[r,:] = l2n( (sum_j mask[r,j]*X[j,:]) / nnz_r ), mask in {0,1} fp32
template<bool TWO>
__global__ __launch_bounds__(256) void k_maskmean(
    const float* __restrict__ mA, const float* __restrict__ mB,
    const float* __restrict__ X, float* __restrict__ outp,
    int rows, int cols, int xB, int xoff, int outB){
  int blk = blockIdx.x;
  int b = blk / rows, r = blk - b*rows;
  int lane = threadIdx.x & 63, wave = threadIdx.x >> 6;
  int wcols = cols >> 2;                          // per-wave column range
  size_t base = ((size_t)b*rows + r) * cols + (size_t)wave*wcols;
  const float* Xb = X + (size_t)b*xB + (size_t)xoff*64 + lane;
  float acc = 0.f; int cnt = 0;
  for (int it = 0; it < wcols; it += 256){        // 64 lanes x 4 fp32 per iter
    int cbase = wave*wcols + it;
    uint4 av = ((const uint4*)(mA + base + it))[lane];
    uint4 bv;
    if (TWO) bv = ((const uint4*)(mB + base + it))[lane];
    #pragma unroll
    for (int s = 0; s < 4; ++s){
      uint32_t wa = (s==0)?av.x:(s==1)?av.y:(s==2)?av.z:av.w;
      bool nz = (wa & 0x7fffffffu) != 0;
      if (TWO){
        uint32_t wb = (s==0)?bv.x:(s==1)?bv.y:(s==2)?bv.z:bv.w;
        nz = nz && ((wb & 0x7fffffffu) != 0);
      }
      u64 m = __ballot(nz);
      cnt += (int)__popcll(m);
      while (m){
        int bit = __builtin_ctzll(m); m &= m - 1;
        int col = cbase + bit*4 + s;
        acc += Xb[(size_t)col * 64];              // coalesced 256B row gather
      }
    }
  }
  __shared__ float sacc[4][64];
  __shared__ int scnt[4];
  sacc[wave][lane] = acc;
  if (lane == 0) scnt[wave] = cnt;
  __syncthreads();
  if (wave == 0){
    float t = sacc[0][lane] + sacc[1][lane] + sacc[2][lane] + sacc[3][lane];
    float deg = (float)(scnt[0] + scnt[1] + scnt[2] + scnt[3]);
    float mean = t / (deg + 1e-30f);
    float ss = mean * mean;
    #pragma unroll
    for (int o = 32; o > 0; o >>= 1) ss += __shfl_xor(ss, o, 64);
    outp[(size_t)b*outB + (size_t)r*64 + lane] = mean / (sqrtf(ss) + 1e-30f);
  }
}

// -------------------- K5: forget gate + update; writes word_updated (out) + WU (ws)
__global__ __launch_bounds__(256, 2) void k_update(
    const float* __restrict__ w0, const float* __restrict__ w1,
    const float* __restrict__ gw, const float* __restrict__ ghat,
    const float* __restrict__ wwkn, const float* __restrict__ wwsn,
    const float* __restrict__ Wf, const float* __restrict__ bf,
    const float* __restrict__ Wupd, const float* __restrict__ bupd,
    float* __restrict__ out, float* __restrict__ WU){
  __shared__ u16 sWf[256*64];     // bf16 weights: 32 KB
  __shared__ u16 sWu[192*64];     // 24 KB
  __shared__ float xsh[4][256];   // 4 KB
  int tid = threadIdx.x;
  for (int i = tid; i < 16384; i += 256) sWf[i] = f2b(Wf[i]);
  for (int i = tid; i < 12288; i += 256) sWu[i] = f2b(Wupd[i]);
  __syncthreads();
  int lane = tid & 63, wave = tid >> 6;
  float bff = bf[lane], bup = bupd[lane];
  for (int t = 0; t < 4; ++t){
    int row = blockIdx.x*4 + wave + t*2048;       // b*4096 + n
    int b = row >> 12, n = row & 4095;
    float aw = (n < 2048) ? w0[((size_t)(b*2048 + n))*64 + lane]
                          : w1[((size_t)(b*2048 + n - 2048))*64 + lane];
    float gv = gw[b*4096 + n];
    float wg = (gv != 0.f) ? ghat[b*64 + lane] : 0.f;
    float wk = wwkn[(size_t)row*64 + lane];
    float wsv = wwsn[(size_t)row*64 + lane];
    xsh[wave][lane] = aw; xsh[wave][64 + lane] = wg;
    xsh[wave][128 + lane] = wk; xsh[wave][192 + lane] = wsv;
    float f = bff, u = bup;
    #pragma unroll 8
    for (int k = 0; k < 64; ++k) f += xsh[wave][k] * b2f(sWf[k*64 + lane]);
    #pragma unroll 8
    for (int k = 64; k < 256; ++k){
      float xv = xsh[wave][k];
      f += xv * b2f(sWf[k*64 + lane]);
      u += xv * b2f(sWu[(k - 64)*64 + lane]);
    }
    f = sigmoidf(f);
    u = fmaxf(u, 0.f);
    float wu = fmaxf(f, 0.2f) * aw + (1.f - f) * u;
    out[((size_t)b*4224 + n)*64 + lane] = wu;
    WU[(size_t)row*64 + lane] = wu;
  }
}

// -------------------- K5b: WUo = WU @ Wo + bo
__global__ __launch_bounds__(256) void k_wuo(
    const float* __restrict__ WU, const float* __restrict__ Wo,
    const float* __restrict__ bo, float* __restrict__ WUo){
  __shared__ float sWo[4096];   // 16 KB fp32
  int tid = threadIdx.x;
  for (int i = tid; i < 1024; i += 256) ((float4*)sWo)[i] = ((const float4*)Wo)[i];
  __syncthreads();
  int lane = tid & 63, wave = tid >> 6;
  float boo = bo[lane];
  for (int t = 0; t < 4; ++t){
    int row = blockIdx.x*4 + wave + t*2048;
    float wu = WU[(size_t)row*64 + lane];
    float o = boo;
    #pragma unroll 8
    for (int d = 0; d < 64; ++d) o += __shfl(wu, d, 64) * sWo[d*64 + lane];
    WUo[(size_t)row*64 + lane] = o;
  }
}

// ------------------- K6: word_op[b,o,:] = (sum_n wes[n]*wop[n,o] * WUo[n,:]) / nnz
__global__ __launch_bounds__(256) void k_opagg(
    const float* __restrict__ wes, const float* __restrict__ wop,
    const float* __restrict__ WUo, float* __restrict__ wordop){
  int blk = blockIdx.x;                           // b*128 + o
  int b = blk >> 7, o = blk & 127;
  int lane = threadIdx.x & 63, wave = threadIdx.x >> 6;
  float acc = 0.f; int cnt = 0;
  for (int it = 0; it < 1024; it += 64){
    int n = wave*1024 + it + lane;
    float a = wes[b*4096 + n];
    float w = wop[((size_t)(b*4096 + n))*128 + o];
    bool nz = (a != 0.f) && (w != 0.f);
    u64 m = __ballot(nz);
    cnt += (int)__popcll(m);
    int nb = wave*1024 + it;
    while (m){
      int bit = __builtin_ctzll(m); m &= m - 1;
      acc += WUo[((size_t)(b*4096 + nb + bit))*64 + lane];
    }
  }
  __shared__ float sacc[4][64];
  __shared__ int scnt[4];
  sacc[wave][lane] = acc;
  if (lane == 0) scnt[wave] = cnt;
  __syncthreads();
  if (wave == 0){
    float t = sacc[0][lane] + sacc[1][lane] + sacc[2][lane] + sacc[3][lane];
    float deg = (float)(scnt[0] + scnt[1] + scnt[2] + scnt[3]);
    wordop[(size_t)blk*64 + lane] = t / (deg + 1e-30f);
  }
}

// ----------------------------------------------------- K7: op_out epilogue
__global__ __launch_bounds__(256) void k_opout(
    const float* __restrict__ opE, const float* __restrict__ wordop,
    const float* __restrict__ Wf2, const float* __restrict__ bf2,
    const float* __restrict__ Wout, const float* __restrict__ bout,
    float* __restrict__ out){
  __shared__ float sW2[8192];   // 32 KB
  __shared__ float sWo[4096];   // 16 KB
  __shared__ float xsh[4][128];
  int tid = threadIdx.x;
  for (int i = tid; i < 2048; i += 256) ((float4*)sW2)[i] = ((const float4*)Wf2)[i];
  for (int i = tid; i < 1024; i += 256) ((float4*)sWo)[i] = ((const float4*)Wout)[i];
  __syncthreads();
  int lane = tid & 63, wave = tid >> 6;
  int row = blockIdx.x*4 + wave;                  // b*128 + o
  int b = row >> 7, o = row & 127;
  float e  = opE[(size_t)row*64 + lane];
  float wo = wordop[(size_t)row*64 + lane];
  xsh[wave][lane] = e; xsh[wave][64 + lane] = wo;
  float f = bf2[lane], u = bout[lane];
  #pragma unroll 8
  for (int k = 0; k < 128; ++k) f += xsh[wave][k] * sW2[k*64 + lane];
  #pragma unroll 8
  for (int d = 0; d < 64; ++d)  u += xsh[wave][64 + d] * sWo[d*64 + lane];
  f = sigmoidf(f);
  u = fmaxf(u, 0.f);
  float res = fmaxf(f, 0.2f) * e + (1.f - f) * u;
  out[((size_t)b*4224 + 4096 + o)*64 + lane] = res;
}

extern "C" void kernel_launch(void* const* d_in, const int* in_sizes, int n_in,
                              void* d_out, int out_size, void* d_ws, size_t ws_size,
                              hipStream_t stream){
  const float* w0   = (const float*)d_in[0];
  const float* w1   = (const float*)d_in[1];
  const float* nh   = (const float*)d_in[2];
  const float* opE  = (const float*)d_in[3];
  const float* wes  = (const float*)d_in[4];
  const float* wem  = (const float*)d_in[5];
  const float* wop  = (const float*)d_in[6];
  const float* ww   = (const float*)d_in[7];
  const float* d0   = (const float*)d_in[8];
  const float* d1   = (const float*)d_in[9];
  const float* gw   = (const float*)d_in[10];
  const float* Wg   = (const float*)d_in[11];
  const float* bg   = (const float*)d_in[12];
  const float* Wwk  = (const float*)d_in[13];
  const float* bwk  = (const float*)d_in[14];
  const float* Wws  = (const float*)d_in[15];
  const float* bws  = (const float*)d_in[16];
  const float* Wo   = (const float*)d_in[17];
  const float* bo   = (const float*)d_in[18];
  const float* Wupd = (const float*)d_in[19];
  const float* bupd = (const float*)d_in[20];
  const float* Wf   = (const float*)d_in[21];
  const float* bf   = (const float*)d_in[22];
  const float* Wf2  = (const float*)d_in[23];
  const float* bf2  = (const float*)d_in[24];
  const float* Wout = (const float*)d_in[25];
  const float* bout = (const float*)d_in[26];

  float* ws   = (float*)d_ws;
  float* ghat = ws;                 // 128
  float* Xk   = ghat + 128;         // 524288
  float* Xs   = Xk + 524288;        // 524288
  float* wwkn = Xs + 524288;        // 524288
  float* wwsn = wwkn + 524288;      // 524288
  float* wopm = wwsn + 524288;      // 16384
  float* WU   = Xk;                 // reuse: Xk dead after k_maskmean<true>
  float* WUo  = Xs;                 // reuse: Xs dead after depend maskmeans
  float* out  = (float*)d_out;

  k_pre<<<1, 128, 0, stream>>>(nh, Wg, bg, ghat);
  k_xform<<<512, 256, 0, stream>>>(w0, w1, Wwk, bwk, Wws, bws, Xk, Xs);
  k_maskmean<true ><<<8192, 256, 0, stream>>>(ww, wem, Xk, wwkn, 4096, 4096, 4096*64, 0,    4096*64);
  k_maskmean<false><<<4096, 256, 0, stream>>>(d0, nullptr, Xs, wwsn,           2048, 2048, 4096*64, 0,    4096*64);
  k_maskmean<false><<<4096, 256, 0, stream>>>(d1, nullptr, Xs, wwsn + 2048*64, 2048, 2048, 4096*64, 2048, 4096*64);
  k_update<<<512, 256, 0, stream>>>(w0, w1, gw, ghat, wwkn, wwsn, Wf, bf, Wupd, bupd, out, WU);
  k_wuo<<<512, 256, 0, stream>>>(WU, Wo, bo, WUo);
  k_opagg<<<256, 256, 0, stream>>>(wes, wop, WUo, wopm);
  k_opout<<<64, 256, 0, stream>>>(opE, wopm, Wf2, bf2, Wout, bout, out);
}

// Round 3
// 454.201 us; speedup vs baseline: 1.0936x; 1.0936x over previous
//
#include <hip/hip_runtime.h>
#include <cstdint>

typedef unsigned short u16;
typedef unsigned long long u64;

__device__ __forceinline__ float b2f(u16 u){
  union { uint32_t i; float f; } v; v.i = ((uint32_t)u) << 16; return v.f;
}
__device__ __forceinline__ u16 f2b(float f){
  union { float f; uint32_t i; } v; v.f = f;
  uint32_t r = v.i + 0x7FFFu + ((v.i >> 16) & 1u);   // RNE
  return (u16)(r >> 16);
}
__device__ __forceinline__ float sigmoidf(float x){ return 1.0f / (1.0f + __expf(-x)); }
__device__ __forceinline__ uint32_t slot(uint4 v, int s){
  return (s==0) ? v.x : (s==1) ? v.y : (s==2) ? v.z : v.w;
}

// ---------------------------------------------------------------- K1: ghat[b,h]
__global__ void k_pre(const float* __restrict__ nh, const float* __restrict__ Wg,
                      const float* __restrict__ bg, float* __restrict__ ghat){
  int b = threadIdx.x >> 6, h = threadIdx.x & 63;
  float g = bg[h];
  for (int d = 0; d < 64; ++d) g += nh[b*64 + d] * Wg[d*64 + h];
  float ss = g * g;
  #pragma unroll
  for (int o = 32; o > 0; o >>= 1) ss += __shfl_xor(ss, o, 64);
  ghat[b*64 + h] = g / (sqrtf(ss) + 1e-30f);
}

// ------------------------------------------- K2: Xk = all_w@Wwk+bwk, Xs = all_w@Wws+bws
__global__ __launch_bounds__(256) void k_xform(
    const float* __restrict__ w0, const float* __restrict__ w1,
    const float* __restrict__ Wwk, const float* __restrict__ bwk,
    const float* __restrict__ Wws, const float* __restrict__ bws,
    float* __restrict__ Xk, float* __restrict__ Xs){
  __shared__ float sWk[4096], sWs[4096];
  int tid = threadIdx.x;
  for (int i = tid; i < 1024; i += 256){
    ((float4*)sWk)[i] = ((const float4*)Wwk)[i];
    ((float4*)sWs)[i] = ((const float4*)Wws)[i];
  }
  __syncthreads();
  int lane = tid & 63, wave = tid >> 6;
  float bk = bwk[lane], bs = bws[lane];
  float aw[4];
  #pragma unroll
  for (int t = 0; t < 4; ++t){
    int row = blockIdx.x*4 + wave + t*2048;
    int b = row >> 12, n = row & 4095;
    aw[t] = (n < 2048) ? w0[((size_t)(b*2048 + n))*64 + lane]
                       : w1[((size_t)(b*2048 + n - 2048))*64 + lane];
  }
  #pragma unroll
  for (int t = 0; t < 4; ++t){
    int row = blockIdx.x*4 + wave + t*2048;
    float xk = bk, xs = bs;
    #pragma unroll 8
    for (int d = 0; d < 64; ++d){
      float a = __shfl(aw[t], d, 64);
      xk += a * sWk[d*64 + lane];
      xs += a * sWs[d*64 + lane];
    }
    Xk[(size_t)row*64 + lane] = xk;
    Xs[(size_t)row*64 + lane] = xs;
  }
}

// ---- K3: out[r,:] = l2n( (sum_j m[r,j]!=0 * X[j,:]) / nnz_r ); 3-phase queue design
// WPR waves per row; each wave scans 1024 cols (4 uint4 per lane per mask).
template<bool TWO, int WPR>
__global__ __launch_bounds__(256) void k_maskmean(
    const float* __restrict__ mA, const float* __restrict__ mB,
    const float* __restrict__ X, float* __restrict__ outp,
    int rows, int cols, int xB, int xoff, int outB){
  __shared__ int q[4][1024];
  __shared__ float sacc[4][64];
  __shared__ int scnt[4];
  constexpr int RPB = 4 / WPR;
  int lane = threadIdx.x & 63, wave = threadIdx.x >> 6;
  int wir = wave & (WPR - 1), sub = wave / WPR;
  int rr = blockIdx.x * RPB + sub;                // flattened (b,r)
  int b = rr / rows, r = rr - b*rows;
  size_t base = ((size_t)b*rows + r) * cols + (size_t)wir*1024;
  const float* Xb = X + (size_t)b*xB + (size_t)xoff*64 + lane;
  // phase 1: preload all mask chunks (8 outstanding loads for TWO, 4 else)
  uint4 av[4], bv[4];
  #pragma unroll
  for (int c = 0; c < 4; ++c){
    av[c] = ((const uint4*)(mA + base))[c*64 + lane];
    if (TWO) bv[c] = ((const uint4*)(mB + base))[c*64 + lane];
  }
  // phase 2: ballot-compact nonzero cols into per-wave LDS queue
  u64 lt = (1ULL << lane) - 1ULL;
  int cnt = 0;
  #pragma unroll
  for (int c = 0; c < 4; ++c){
    #pragma unroll
    for (int s = 0; s < 4; ++s){
      bool nz = (slot(av[c], s) & 0x7fffffffu) != 0;
      if (TWO) nz = nz && ((slot(bv[c], s) & 0x7fffffffu) != 0);
      u64 m = __ballot(nz);
      if (nz) q[wave][cnt + (int)__popcll(m & lt)] = wir*1024 + c*256 + lane*4 + s;
      cnt += (int)__popcll(m);
    }
  }
  // phase 3: batched gathers (8 independent coalesced 256B loads per batch)
  float acc = 0.f;
  int i = 0;
  for (; i + 8 <= cnt; i += 8){
    int4 c0 = *(const int4*)&q[wave][i];
    int4 c1 = *(const int4*)&q[wave][i + 4];
    float v0 = Xb[(size_t)c0.x*64], v1 = Xb[(size_t)c0.y*64];
    float v2 = Xb[(size_t)c0.z*64], v3 = Xb[(size_t)c0.w*64];
    float v4 = Xb[(size_t)c1.x*64], v5 = Xb[(size_t)c1.y*64];
    float v6 = Xb[(size_t)c1.z*64], v7 = Xb[(size_t)c1.w*64];
    acc += ((v0 + v1) + (v2 + v3)) + ((v4 + v5) + (v6 + v7));
  }
  for (; i < cnt; ++i) acc += Xb[(size_t)q[wave][i]*64];
  sacc[wave][lane] = acc;
  if (lane == 0) scnt[wave] = cnt;
  __syncthreads();
  if (wir == 0){
    float t = 0.f; int dg = 0;
    #pragma unroll
    for (int j = 0; j < WPR; ++j){ t += sacc[sub*WPR + j][lane]; dg += scnt[sub*WPR + j]; }
    float mean = t / ((float)dg + 1e-30f);
    float ss = mean * mean;
    #pragma unroll
    for (int o = 32; o > 0; o >>= 1) ss += __shfl_xor(ss, o, 64);
    outp[(size_t)b*outB + (size_t)r*64 + lane] = mean / (sqrtf(ss) + 1e-30f);
  }
}

// -------------------- K5: forget gate + update; packed bf16-pair weights in LDS
__global__ __launch_bounds__(256, 2) void k_update(
    const float* __restrict__ w0, const float* __restrict__ w1,
    const float* __restrict__ gw, const float* __restrict__ ghat,
    const float* __restrict__ wwkn, const float* __restrict__ wwsn,
    const float* __restrict__ Wf, const float* __restrict__ bf,
    const float* __restrict__ Wupd, const float* __restrict__ bupd,
    float* __restrict__ out, float* __restrict__ WU){
  __shared__ uint32_t pWf[128*64];   // 32 KB: (bf16 W[2k][d], bf16 W[2k+1][d])
  __shared__ uint32_t pWu[96*64];    // 24 KB
  __shared__ float xsh[4][256];      // 4 KB
  int tid = threadIdx.x;
  for (int i = tid; i < 8192; i += 256){
    int k2 = i >> 6, ln = i & 63;
    pWf[i] = (uint32_t)f2b(Wf[(2*k2)*64 + ln]) | ((uint32_t)f2b(Wf[(2*k2+1)*64 + ln]) << 16);
  }
  for (int i = tid; i < 6144; i += 256){
    int k2 = i >> 6, ln = i & 63;
    pWu[i] = (uint32_t)f2b(Wupd[(2*k2)*64 + ln]) | ((uint32_t)f2b(Wupd[(2*k2+1)*64 + ln]) << 16);
  }
  __syncthreads();
  int lane = tid & 63, wave = tid >> 6;
  float bff = bf[lane], bup = bupd[lane];
  float aw[4], wgv[4], wk[4], wsv[4];
  #pragma unroll
  for (int t = 0; t < 4; ++t){
    int row = blockIdx.x*4 + wave + t*2048;
    int b = row >> 12, n = row & 4095;
    aw[t] = (n < 2048) ? w0[((size_t)(b*2048 + n))*64 + lane]
                       : w1[((size_t)(b*2048 + n - 2048))*64 + lane];
    float gvv = gw[b*4096 + n];
    wgv[t] = (gvv != 0.f) ? ghat[b*64 + lane] : 0.f;
    wk[t]  = wwkn[(size_t)row*64 + lane];
    wsv[t] = wwsn[(size_t)row*64 + lane];
  }
  #pragma unroll
  for (int t = 0; t < 4; ++t){
    int row = blockIdx.x*4 + wave + t*2048;
    int b = row >> 12, n = row & 4095;
    xsh[wave][lane] = aw[t]; xsh[wave][64 + lane] = wgv[t];
    xsh[wave][128 + lane] = wk[t]; xsh[wave][192 + lane] = wsv[t];
    float f = bff, u = bup;
    #pragma unroll 8
    for (int k2 = 0; k2 < 32; ++k2){
      float2 xv = *(const float2*)&xsh[wave][2*k2];
      uint32_t wf = pWf[k2*64 + lane];
      f += xv.x * b2f((u16)wf) + xv.y * b2f((u16)(wf >> 16));
    }
    #pragma unroll 8
    for (int k2 = 32; k2 < 128; ++k2){
      float2 xv = *(const float2*)&xsh[wave][2*k2];
      uint32_t wf = pWf[k2*64 + lane];
      uint32_t wu = pWu[(k2 - 32)*64 + lane];
      f += xv.x * b2f((u16)wf) + xv.y * b2f((u16)(wf >> 16));
      u += xv.x * b2f((u16)wu) + xv.y * b2f((u16)(wu >> 16));
    }
    f = sigmoidf(f);
    u = fmaxf(u, 0.f);
    float wu = fmaxf(f, 0.2f) * aw[t] + (1.f - f) * u;
    out[((size_t)b*4224 + n)*64 + lane] = wu;
    WU[(size_t)row*64 + lane] = wu;
  }
}

// -------------------- K5b: WUo = WU @ Wo + bo
__global__ __launch_bounds__(256) void k_wuo(
    const float* __restrict__ WU, const float* __restrict__ Wo,
    const float* __restrict__ bo, float* __restrict__ WUo){
  __shared__ float sWo[4096];
  int tid = threadIdx.x;
  for (int i = tid; i < 1024; i += 256) ((float4*)sWo)[i] = ((const float4*)Wo)[i];
  __syncthreads();
  int lane = tid & 63, wave = tid >> 6;
  float boo = bo[lane];
  float wu[4];
  #pragma unroll
  for (int t = 0; t < 4; ++t){
    int row = blockIdx.x*4 + wave + t*2048;
    wu[t] = WU[(size_t)row*64 + lane];
  }
  #pragma unroll
  for (int t = 0; t < 4; ++t){
    int row = blockIdx.x*4 + wave + t*2048;
    float o = boo;
    #pragma unroll 8
    for (int d = 0; d < 64; ++d) o += __shfl(wu[t], d, 64) * sWo[d*64 + lane];
    WUo[(size_t)row*64 + lane] = o;
  }
}

// ------------------- K6: word_op[b,o,:] = (sum_n wes[n]*wop[n,o]!=0 * WUo[n,:]) / nnz
__global__ __launch_bounds__(256) void k_opagg(
    const float* __restrict__ wes, const float* __restrict__ wop,
    const float* __restrict__ WUo, float* __restrict__ wordop){
  __shared__ int q[4][1024];
  __shared__ float sacc[4][64];
  __shared__ int scnt[4];
  int blk = blockIdx.x;                           // b*128 + o
  int b = blk >> 7, o = blk & 127;
  int lane = threadIdx.x & 63, wave = threadIdx.x >> 6;
  const float* wesb = wes + b*4096 + wave*1024;
  const float* Xb = WUo + (size_t)b*4096*64 + lane;
  uint4 av[4]; float wv[16];
  #pragma unroll
  for (int c = 0; c < 4; ++c) av[c] = ((const uint4*)wesb)[c*64 + lane];
  #pragma unroll
  for (int c = 0; c < 4; ++c)
    #pragma unroll
    for (int s = 0; s < 4; ++s)
      wv[c*4 + s] = wop[(size_t)(b*4096 + wave*1024 + c*256 + lane*4 + s)*128 + o];
  u64 lt = (1ULL << lane) - 1ULL;
  int cnt = 0;
  #pragma unroll
  for (int c = 0; c < 4; ++c){
    #pragma unroll
    for (int s = 0; s < 4; ++s){
      bool nz = ((slot(av[c], s) & 0x7fffffffu) != 0) && (wv[c*4 + s] != 0.f);
      u64 m = __ballot(nz);
      if (nz) q[wave][cnt + (int)__popcll(m & lt)] = wave*1024 + c*256 + lane*4 + s;
      cnt += (int)__popcll(m);
    }
  }
  float acc = 0.f;
  int i = 0;
  for (; i + 8 <= cnt; i += 8){
    int4 c0 = *(const int4*)&q[wave][i];
    int4 c1 = *(const int4*)&q[wave][i + 4];
    float v0 = Xb[(size_t)c0.x*64], v1 = Xb[(size_t)c0.y*64];
    float v2 = Xb[(size_t)c0.z*64], v3 = Xb[(size_t)c0.w*64];
    float v4 = Xb[(size_t)c1.x*64], v5 = Xb[(size_t)c1.y*64];
    float v6 = Xb[(size_t)c1.z*64], v7 = Xb[(size_t)c1.w*64];
    acc += ((v0 + v1) + (v2 + v3)) + ((v4 + v5) + (v6 + v7));
  }
  for (; i < cnt; ++i) acc += Xb[(size_t)q[wave][i]*64];
  sacc[wave][lane] = acc;
  if (lane == 0) scnt[wave] = cnt;
  __syncthreads();
  if (wave == 0){
    float t = sacc[0][lane] + sacc[1][lane] + sacc[2][lane] + sacc[3][lane];
    float deg = (float)(scnt[0] + scnt[1] + scnt[2] + scnt[3]);
    wordop[(size_t)blk*64 + lane] = t / (deg + 1e-30f);
  }
}

// ----------------------------------------------------- K7: op_out epilogue
__global__ __launch_bounds__(256) void k_opout(
    const float* __restrict__ opE, const float* __restrict__ wordop,
    const float* __restrict__ Wf2, const float* __restrict__ bf2,
    const float* __restrict__ Wout, const float* __restrict__ bout,
    float* __restrict__ out){
  __shared__ float sW2[8192];
  __shared__ float sWo[4096];
  __shared__ float xsh[4][128];
  int tid = threadIdx.x;
  for (int i = tid; i < 2048; i += 256) ((float4*)sW2)[i] = ((const float4*)Wf2)[i];
  for (int i = tid; i < 1024; i += 256) ((float4*)sWo)[i] = ((const float4*)Wout)[i];
  __syncthreads();
  int lane = tid & 63, wave = tid >> 6;
  int row = blockIdx.x*4 + wave;                  // b*128 + o
  int b = row >> 7, o = row & 127;
  float e  = opE[(size_t)row*64 + lane];
  float wo = wordop[(size_t)row*64 + lane];
  xsh[wave][lane] = e; xsh[wave][64 + lane] = wo;
  float f = bf2[lane], u = bout[lane];
  #pragma unroll 8
  for (int k = 0; k < 128; ++k) f += xsh[wave][k] * sW2[k*64 + lane];
  #pragma unroll 8
  for (int d = 0; d < 64; ++d)  u += xsh[wave][64 + d] * sWo[d*64 + lane];
  f = sigmoidf(f);
  u = fmaxf(u, 0.f);
  float res = fmaxf(f, 0.2f) * e + (1.f - f) * u;
  out[((size_t)b*4224 + 4096 + o)*64 + lane] = res;
}

extern "C" void kernel_launch(void* const* d_in, const int* in_sizes, int n_in,
                              void* d_out, int out_size, void* d_ws, size_t ws_size,
                              hipStream_t stream){
  const float* w0   = (const float*)d_in[0];
  const float* w1   = (const float*)d_in[1];
  const float* nh   = (const float*)d_in[2];
  const float* opE  = (const float*)d_in[3];
  const float* wes  = (const float*)d_in[4];
  const float* wem  = (const float*)d_in[5];
  const float* wop  = (const float*)d_in[6];
  const float* ww   = (const float*)d_in[7];
  const float* d0   = (const float*)d_in[8];
  const float* d1   = (const float*)d_in[9];
  const float* gw   = (const float*)d_in[10];
  const float* Wg   = (const float*)d_in[11];
  const float* bg   = (const float*)d_in[12];
  const float* Wwk  = (const float*)d_in[13];
  const float* bwk  = (const float*)d_in[14];
  const float* Wws  = (const float*)d_in[15];
  const float* bws  = (const float*)d_in[16];
  const float* Wo   = (const float*)d_in[17];
  const float* bo   = (const float*)d_in[18];
  const float* Wupd = (const float*)d_in[19];
  const float* bupd = (const float*)d_in[20];
  const float* Wf   = (const float*)d_in[21];
  const float* bf   = (const float*)d_in[22];
  const float* Wf2  = (const float*)d_in[23];
  const float* bf2  = (const float*)d_in[24];
  const float* Wout = (const float*)d_in[25];
  const float* bout = (const float*)d_in[26];

  float* ws   = (float*)d_ws;
  float* ghat = ws;                 // 128
  float* Xk   = ghat + 128;         // 524288
  float* Xs   = Xk + 524288;        // 524288
  float* wwkn = Xs + 524288;        // 524288
  float* wwsn = wwkn + 524288;      // 524288
  float* wopm = wwsn + 524288;      // 16384
  float* WU   = Xk;                 // reuse: Xk dead after big maskmean
  float* WUo  = Xs;                 // reuse: Xs dead after depend maskmeans
  float* out  = (float*)d_out;

  k_pre<<<1, 128, 0, stream>>>(nh, Wg, bg, ghat);
  k_xform<<<512, 256, 0, stream>>>(w0, w1, Wwk, bwk, Wws, bws, Xk, Xs);
  k_maskmean<true , 4><<<8192, 256, 0, stream>>>(ww, wem, Xk, wwkn, 4096, 4096, 4096*64, 0,    4096*64);
  k_maskmean<false, 2><<<2048, 256, 0, stream>>>(d0, nullptr, Xs, wwsn,           2048, 2048, 4096*64, 0,    4096*64);
  k_maskmean<false, 2><<<2048, 256, 0, stream>>>(d1, nullptr, Xs, wwsn + 2048*64, 2048, 2048, 4096*64, 2048, 4096*64);
  k_update<<<512, 256, 0, stream>>>(w0, w1, gw, ghat, wwkn, wwsn, Wf, bf, Wupd, bupd, out, WU);
  k_wuo<<<512, 256, 0, stream>>>(WU, Wo, bo, WUo);
  k_opagg<<<256, 256, 0, stream>>>(wes, wop, WUo, wopm);
  k_opout<<<64, 256, 0, stream>>>(opE, wopm, Wf2, bf2, Wout, bout, out);
}